// Round 11
// baseline (454.880 us; speedup 1.0000x reference)
//
#include <hip/hip_runtime.h>
#include <hip/hip_bf16.h>
#include <cstdint>

#define P_ 88   // pitches (sequence length of the scan)
#define B_ 16   // batch
#define T_ 256  // timesteps (folded into batch N)
#define H_ 188  // per-pitch features
#define G_ 192  // 4*48 gates; also LSTM1 input size (188 feat + 4 ctx)
#define U_ 48   // LSTM units
#define N_ 4096 // B_*T_

typedef __attribute__((ext_vector_type(8))) short bf16x8;
typedef __attribute__((ext_vector_type(8))) _Float16 f16x8;
typedef __attribute__((ext_vector_type(4))) float f32x4;

__device__ __forceinline__ float sigf(float x) {
  return __builtin_amdgcn_rcpf(1.0f + __expf(-x));
}
__device__ __forceinline__ float tanh_f(float x) {
  return 1.0f - 2.0f * __builtin_amdgcn_rcpf(1.0f + __expf(2.0f * x));
}
__device__ __forceinline__ unsigned short f2bs(float v) {
  union { __hip_bfloat16 h; unsigned short s; } u;
  u.h = __float2bfloat16(v);
  return u.s;
}
__device__ __forceinline__ float bs2f(unsigned short s) {
  union { unsigned int u; float f; } x;
  x.u = ((unsigned int)s) << 16;
  return x.f;
}
__device__ __forceinline__ float hs2f(unsigned short s) {
  union { unsigned short u; _Float16 h; } x;
  x.u = s;
  return (float)x.h;
}
__device__ __forceinline__ unsigned short f2hs(float v) {
  union { _Float16 h; unsigned short s; } x;
  x.h = (_Float16)v;
  return x.s;
}
// truncation-based hi/lo bf16 split (hi+lo == h to ~2^-17; cheaper than RNE)
__device__ __forceinline__ void hsplit(float h, unsigned short& hi, unsigned short& lo) {
  union { float f; unsigned int u; } x;
  x.f = h;
  hi = (unsigned short)(x.u >> 16);
  union { float f; unsigned int u; } y;
  y.f = h - bs2f(hi);
  lo = (unsigned short)(y.u >> 16);
}

// Relaxed workgroup barrier: waits only on LDS ops (lgkmcnt), NOT vmcnt.
__device__ __forceinline__ void lds_barrier() {
  asm volatile("s_waitcnt lgkmcnt(0)\n\ts_barrier" ::: "memory");
}
__device__ __forceinline__ void lds_wave_fence() {
  asm volatile("s_waitcnt lgkmcnt(0)" ::: "memory");
}

// Scrambled gate->slot map: wave ws owns all 4 gate types for units
// u in [ws*12, ws*12+12). For gate g: slot base (excl. r*64 + q*16).
__device__ __forceinline__ int scan_slot(int g) {
  const int t = g / 48;
  const int u = g - t * 48;
  const int ws = u / 12;
  const int ul = u - ws * 12;
  const int c = t * 12 + ul;             // col within the wave's 48
  return (ws * 3 + (c >> 4)) * 256 + (c & 15);
}

// ---------------------------------------------------------------------------
// Kernel 1: context MLP -> per-(b,p) gate bias vector
// ---------------------------------------------------------------------------
__global__ void ctx_kernel(const float* __restrict__ pc,
                           const float* __restrict__ fc1w, const float* __restrict__ fc1b,
                           const float* __restrict__ fc2w, const float* __restrict__ fc2b,
                           const float* __restrict__ fc3w, const float* __restrict__ fc3b,
                           const float* __restrict__ wih1,
                           const float* __restrict__ bih1, const float* __restrict__ bhh1,
                           float* __restrict__ ctxg) {
  int bp = blockIdx.x * 64 + threadIdx.x;
  if (bp >= B_ * P_) return;
  float p0 = pc[bp * 3 + 0], p1 = pc[bp * 3 + 1], p2 = pc[bp * 3 + 2];
  float x1[16], x2[16];
#pragma unroll
  for (int jj = 0; jj < 16; ++jj)
    x1[jj] = fmaxf(0.f, fc1w[jj * 3 + 0] * p0 + fc1w[jj * 3 + 1] * p1 + fc1w[jj * 3 + 2] * p2 + fc1b[jj]);
#pragma unroll
  for (int jj = 0; jj < 16; ++jj) {
    float s = fc2b[jj];
#pragma unroll
    for (int i = 0; i < 16; ++i) s += fc2w[jj * 16 + i] * x1[i];
    x2[jj] = fmaxf(0.f, s);
  }
  float ce[4];
#pragma unroll
  for (int jj = 0; jj < 4; ++jj) {
    float s = fc3b[jj];
#pragma unroll
    for (int i = 0; i < 16; ++i) s += fc3w[jj * 16 + i] * x2[i];
    ce[jj] = s;
  }
  float* op = ctxg + (size_t)bp * G_;
  for (int g = 0; g < G_; ++g) {
    const float* wr = wih1 + (size_t)g * G_ + H_;
    op[g] = bih1[g] + bhh1[g] + ce[0] * wr[0] + ce[1] * wr[1] + ce[2] * wr[2] + ce[3] * wr[3];
  }
}

// ---------------------------------------------------------------------------
// Kernel 1b: pack wih1 feature columns into f16 MFMA B-fragment order.
// ---------------------------------------------------------------------------
__global__ __launch_bounds__(256) void wfrag_kernel(const float* __restrict__ wih1,
                                                    f16x8* __restrict__ wfrag) {
  const int idx = blockIdx.x * 256 + threadIdx.x;
  if (idx >= 12 * 6 * 64) return;
  const int l = idx & 63;
  const int kc = (idx >> 6) % 6;
  const int j = idx / 384;
  const int g = j * 16 + (l & 15);
  const int k0 = kc * 32 + (l >> 4) * 8;
  f16x8 v;
#pragma unroll
  for (int e = 0; e < 8; ++e) {
    const int k = k0 + e;
    const float wv = (k < H_) ? wih1[(size_t)g * G_ + k] : 0.f;
    v[e] = (_Float16)wv;
  }
  wfrag[idx] = v;
}

// ---------------------------------------------------------------------------
// Kernel 2: MFMA GEMM (LDS-staged A, LDS-repacked stores). Epilogue now
// scatters into the scan's SCRAMBLED gate order via scan_slot().
// ---------------------------------------------------------------------------
__global__ __launch_bounds__(256, 3) void gemm_mfma(const float* __restrict__ pf,
                                                    const f16x8* __restrict__ wfrag,
                                                    const float* __restrict__ ctxg,
                                                    unsigned short* __restrict__ xg2) {
  const int bp = blockIdx.x >> 1, tb = blockIdx.x & 1;
  const int p = bp % P_, b = bp / P_;
  const int tid = threadIdx.x;
  const int w = tid >> 6, l = tid & 63;
  const int lj = l & 15, lq = l >> 4;

  __shared__ __align__(16) char ldsraw[49152];
  _Float16(*Ahi)[34] = (_Float16(*)[34])ldsraw;
  _Float16(*Alo)[34] = (_Float16(*)[34])(ldsraw + 8704);

  float cg[12];
#pragma unroll
  for (int jn = 0; jn < 12; ++jn)
    cg[jn] = ctxg[(size_t)bp * G_ + jn * 16 + lj];

  f32x4 acc[2][12];
#pragma unroll
  for (int mt = 0; mt < 2; ++mt)
#pragma unroll
    for (int jn = 0; jn < 12; ++jn)
#pragma unroll
      for (int r = 0; r < 4; ++r) acc[mt][jn][r] = 0.f;

  const float* Ab = pf + (size_t)bp * H_ * T_ + tb * 128;
  const int kl = tid >> 5;
  const int t4 = (tid & 31) * 4;

  for (int kc = 0; kc < 6; ++kc) {
    __syncthreads();
#pragma unroll
    for (int rr = 0; rr < 4; ++rr) {
      const int kk = rr * 8 + kl;
      const int kg = kc * 32 + kk;
      float a0 = 0.f, a1 = 0.f, a2 = 0.f, a3 = 0.f;
      if (kg < H_) {
        const float4 v = *(const float4*)(Ab + (size_t)kg * T_ + t4);
        a0 = v.x; a1 = v.y; a2 = v.z; a3 = v.w;
      }
      const _Float16 h0 = (_Float16)a0, h1 = (_Float16)a1;
      const _Float16 h2 = (_Float16)a2, h3 = (_Float16)a3;
      Ahi[t4 + 0][kk] = h0; Alo[t4 + 0][kk] = (_Float16)(a0 - (float)h0);
      Ahi[t4 + 1][kk] = h1; Alo[t4 + 1][kk] = (_Float16)(a1 - (float)h1);
      Ahi[t4 + 2][kk] = h2; Alo[t4 + 2][kk] = (_Float16)(a2 - (float)h2);
      Ahi[t4 + 3][kk] = h3; Alo[t4 + 3][kk] = (_Float16)(a3 - (float)h3);
    }
    __syncthreads();
    const int trow = w * 32;
    const f16x8 ahi0 = *(const f16x8*)&Ahi[trow + lj][lq * 8];
    const f16x8 ahi1 = *(const f16x8*)&Ahi[trow + 16 + lj][lq * 8];
    const f16x8 alo0 = *(const f16x8*)&Alo[trow + lj][lq * 8];
    const f16x8 alo1 = *(const f16x8*)&Alo[trow + 16 + lj][lq * 8];
#pragma unroll
    for (int jn = 0; jn < 12; ++jn) {
      const f16x8 wf = wfrag[(jn * 6 + kc) * 64 + l];
      acc[0][jn] = __builtin_amdgcn_mfma_f32_16x16x32_f16(ahi0, wf, acc[0][jn], 0, 0, 0);
      acc[1][jn] = __builtin_amdgcn_mfma_f32_16x16x32_f16(ahi1, wf, acc[1][jn], 0, 0, 0);
      acc[0][jn] = __builtin_amdgcn_mfma_f32_16x16x32_f16(alo0, wf, acc[0][jn], 0, 0, 0);
      acc[1][jn] = __builtin_amdgcn_mfma_f32_16x16x32_f16(alo1, wf, acc[1][jn], 0, 0, 0);
    }
  }
  __syncthreads();

  // epilogue: + ctx bias, f16, scatter into scrambled scan order via LDS,
  // then uint4 coalesced global stores.
  unsigned short* Cst = (unsigned short*)ldsraw + w * 6144;
#pragma unroll
  for (int mt = 0; mt < 2; ++mt)
#pragma unroll
    for (int jn = 0; jn < 12; ++jn) {
      const int sbase = scan_slot(jn * 16 + lj) + lq * 16;
#pragma unroll
      for (int r = 0; r < 4; ++r)
        Cst[mt * 3072 + sbase + r * 64] = f2hs(acc[mt][jn][r] + cg[jn]);
    }
  const int nb0 = b * 16 + tb * 8 + w * 2;
  unsigned short* gb = xg2 + ((size_t)p * 256 + nb0) * 3072;
#pragma unroll
  for (int rr = 0; rr < 12; ++rr) {
    const uint4 v = *(const uint4*)(Cst + rr * 512 + l * 8);
    *(uint4*)(gb + rr * 512 + l * 8) = v;
  }
}

// ---------------------------------------------------------------------------
// Kernel 3: MFMA persistent scan, 2 barriers/step.
// Wave w owns gate cols {t*48 + w*12 + u_loc}: gate production -> activation
// is WAVE-LOCAL (per-wave gsw scratch + lgkmcnt fence, no barrier).
// h is double-buffered by step parity: phase1 reads h1 from buf[alt], writes
// h1(p) to buf[cur]; phase2 reads buf[cur] (h1(p)+h2(p-1)), writes h2(p) to
// buf[alt]. fc/softmax/store tasks spread evenly across waves.
// ---------------------------------------------------------------------------
__global__ __launch_bounds__(256, 2) void scan_mfma(
    const unsigned short* __restrict__ xg2,
    const float* __restrict__ whh1, const float* __restrict__ wih2,
    const float* __restrict__ whh2, const float* __restrict__ bih2,
    const float* __restrict__ bhh2, const float* __restrict__ fcw,
    const float* __restrict__ fcb, float* __restrict__ out) {
  __shared__ __align__(16) short hh[2][16][104];  // hi bits: cols 0-47 h1, 48-95 h2
  __shared__ __align__(16) short hl[2][16][104];  // lo bits
  __shared__ __align__(16) float gsw[4][8][52];   // per-wave gate scratch
  __shared__ __align__(16) float h2f[8][52];      // h2 fp32 for fc_states
  __shared__ __align__(16) float fcws[5 * 48];
  __shared__ float logit_s[5][8];
  __shared__ float prob_s[5][8];

  const int tid = threadIdx.x;
  const int w = tid >> 6;
  const int l = tid & 63;
  const int lj = l & 15;
  const int lq = l >> 4;
  const int grp = blockIdx.x >> 1;
  const int half = blockIdx.x & 1;
  const int n0 = blockIdx.x * 8;
  const int b = n0 >> 8, t0 = n0 & 255;

  // ---- persistent weight B-fragments, SCRAMBLED gate mapping ----
  // col c = i*16+lj -> type t=c/12, u_loc=c%12, gate j = t*48 + w*12 + u_loc
  bf16x8 b1[3][2];
  bf16x8 b2f[3][3];
  float bias2r[3];
#pragma unroll
  for (int i = 0; i < 3; ++i) {
    const int c = i * 16 + lj;
    const int t = c / 12, ul = c - t * 12;
    const int j = t * 48 + w * 12 + ul;
    bias2r[i] = bih2[j] + bhh2[j];
#pragma unroll
    for (int kc = 0; kc < 2; ++kc)
#pragma unroll
      for (int e = 0; e < 8; ++e) {
        const int u = kc * 32 + lq * 8 + e;
        b1[i][kc][e] = (u < U_) ? (short)f2bs(whh1[j * U_ + u]) : (short)0;
      }
#pragma unroll
    for (int kc = 0; kc < 3; ++kc)
#pragma unroll
      for (int e = 0; e < 8; ++e) {
        const int k = kc * 32 + lq * 8 + e;
        b2f[i][kc][e] = (k < U_) ? (short)f2bs(wih2[j * U_ + k])
                                 : (short)f2bs(whh2[j * U_ + (k - U_)]);
      }
  }

  for (int e = tid; e < 2 * 16 * 104 / 2; e += 256) {
    ((unsigned int*)hh)[e] = 0u;
    ((unsigned int*)hl)[e] = 0u;
  }
  for (int e = tid; e < 5 * U_; e += 256) fcws[e] = fcw[e];

  // activation tasks (wave-local): 96 tasks = 8n x 12u; slot0 = l, slot1 = 64+l (l<32)
  const int an0 = l / 12, au0 = l - an0 * 12;
  const int an1 = (64 + l) / 12, au1 = (64 + l) - an1 * 12;
  const int aug0 = w * 12 + au0, aug1 = w * 12 + au1;
  const bool has2 = (l < 32);
  float c1s[2] = {0.f, 0.f}, c2s[2] = {0.f, 0.f};

  // aux roles, balanced across waves: lanes 0-9 fc-logit, 10-19 store, 20-21 softmax
  const bool fcth = (l < 10);
  const int tf = w * 10 + l;            // fc task: k = tf/8, n = tf%8
  const int fk = tf >> 3, fn = tf & 7;
  const float fcbr = fcth ? fcb[fk] : 0.f;
  const bool stth = (l >= 10 && l < 20);
  const int ts = w * 10 + (l - 10);
  const int sk = ts >> 3, sn = ts & 7;
  const bool smth = (l >= 20 && l < 22);
  const int sm = w * 2 + (l - 20);      // softmax task n = sm

  // xg prefetch for p=0 (lanes lq<2 hold rows half*8 + lq*4+r)
  unsigned short xp[12];
  {
    const size_t pb = (size_t)grp * 3072;
#pragma unroll
    for (int i = 0; i < 3; ++i)
#pragma unroll
      for (int r = 0; r < 4; ++r)
        xp[i * 4 + r] = (lq < 2)
            ? xg2[pb + (size_t)((w * 3 + i) * 256 + r * 64 + (half * 2 + lq) * 16 + lj)]
            : (unsigned short)0;
  }
  lds_barrier();

  for (int p = 0; p < P_; ++p) {
    const int cur = p & 1, alt = cur ^ 1;
    // ================= PHASE 1: L1 =================
    f32x4 cH[3], cL[3];
#pragma unroll
    for (int i = 0; i < 3; ++i)
#pragma unroll
      for (int r = 0; r < 4; ++r) { cH[i][r] = hs2f(xp[i * 4 + r]); cL[i][r] = 0.f; }
    if (p < P_ - 1) {  // issue next-step loads; in flight across both barriers
      const size_t pb = (size_t)((p + 1) * 256 + grp) * 3072;
#pragma unroll
      for (int i = 0; i < 3; ++i)
#pragma unroll
        for (int r = 0; r < 4; ++r)
          xp[i * 4 + r] = (lq < 2)
              ? xg2[pb + (size_t)((w * 3 + i) * 256 + r * 64 + (half * 2 + lq) * 16 + lj)]
              : (unsigned short)0;
    }
    {
      const short* hr = &hh[alt][lj][0];
      const short* lr = &hl[alt][lj][0];
      bf16x8 ah0 = *(const bf16x8*)(hr + lq * 8);
      bf16x8 ah1 = *(const bf16x8*)(hr + 32 + lq * 8);
      bf16x8 al0 = *(const bf16x8*)(lr + lq * 8);
      bf16x8 al1 = *(const bf16x8*)(lr + 32 + lq * 8);
#pragma unroll
      for (int i = 0; i < 3; ++i)
        cH[i] = __builtin_amdgcn_mfma_f32_16x16x32_bf16(ah0, b1[i][0], cH[i], 0, 0, 0);
#pragma unroll
      for (int i = 0; i < 3; ++i)
        cL[i] = __builtin_amdgcn_mfma_f32_16x16x32_bf16(al0, b1[i][0], cL[i], 0, 0, 0);
#pragma unroll
      for (int i = 0; i < 3; ++i)
        cH[i] = __builtin_amdgcn_mfma_f32_16x16x32_bf16(ah1, b1[i][1], cH[i], 0, 0, 0);
#pragma unroll
      for (int i = 0; i < 3; ++i)
        cL[i] = __builtin_amdgcn_mfma_f32_16x16x32_bf16(al1, b1[i][1], cL[i], 0, 0, 0);
    }
    if (lq < 2) {
#pragma unroll
      for (int i = 0; i < 3; ++i)
#pragma unroll
        for (int r = 0; r < 4; ++r)
          gsw[w][lq * 4 + r][i * 16 + lj] = cH[i][r] + cL[i][r];
    }
    // fc logits for p-1 (reads h2f, stable until phase 2)
    if (p > 0 && fcth) {
      float a = fcbr;
#pragma unroll
      for (int uq = 0; uq < 12; ++uq) {
        f32x4 hv = *(const f32x4*)&h2f[fn][uq * 4];
        f32x4 wv = *(const f32x4*)&fcws[fk * 48 + uq * 4];
        a += hv[0] * wv[0] + hv[1] * wv[1] + hv[2] * wv[2] + hv[3] * wv[3];
      }
      logit_s[fk][fn] = a;
    }
    // store probs for p-2
    if (p > 1 && stth) {
      out[(((size_t)b * P_ + (p - 2)) * 5 + sk) * T_ + t0 + sn] = prob_s[sk][sn];
    }
    lds_wave_fence();  // gsw writes visible to this wave's own lanes
    // L1 activations (wave-local) -> h1(p) into buf[cur]
    {
      const float ig = gsw[w][an0][au0],      fg = gsw[w][an0][12 + au0];
      const float gg = gsw[w][an0][24 + au0], og = gsw[w][an0][36 + au0];
      const float cc = sigf(fg) * c1s[0] + sigf(ig) * tanh_f(gg);
      c1s[0] = cc;
      const float h = sigf(og) * tanh_f(cc);
      unsigned short hb, lb;
      hsplit(h, hb, lb);
      hh[cur][an0][aug0] = (short)hb;
      hl[cur][an0][aug0] = (short)lb;
    }
    if (has2) {
      const float ig = gsw[w][an1][au1],      fg = gsw[w][an1][12 + au1];
      const float gg = gsw[w][an1][24 + au1], og = gsw[w][an1][36 + au1];
      const float cc = sigf(fg) * c1s[1] + sigf(ig) * tanh_f(gg);
      c1s[1] = cc;
      const float h = sigf(og) * tanh_f(cc);
      unsigned short hb, lb;
      hsplit(h, hb, lb);
      hh[cur][an1][aug1] = (short)hb;
      hl[cur][an1][aug1] = (short)lb;
    }
    lds_barrier();  // B1
    // ================= PHASE 2: L2 =================
    f32x4 c2H[3], c2L[3];
#pragma unroll
    for (int i = 0; i < 3; ++i) {
      c2H[i][0] = bias2r[i]; c2H[i][1] = bias2r[i];
      c2H[i][2] = bias2r[i]; c2H[i][3] = bias2r[i];
      c2L[i][0] = 0.f; c2L[i][1] = 0.f; c2L[i][2] = 0.f; c2L[i][3] = 0.f;
    }
    {
      const short* hr = &hh[cur][lj][0];
      const short* lr = &hl[cur][lj][0];
      bf16x8 a0 = *(const bf16x8*)(hr + lq * 8);
      bf16x8 a1 = *(const bf16x8*)(hr + 32 + lq * 8);
      bf16x8 a2 = *(const bf16x8*)(hr + 64 + lq * 8);
      bf16x8 q0 = *(const bf16x8*)(lr + lq * 8);
      bf16x8 q1 = *(const bf16x8*)(lr + 32 + lq * 8);
      bf16x8 q2 = *(const bf16x8*)(lr + 64 + lq * 8);
#pragma unroll
      for (int i = 0; i < 3; ++i)
        c2H[i] = __builtin_amdgcn_mfma_f32_16x16x32_bf16(a0, b2f[i][0], c2H[i], 0, 0, 0);
#pragma unroll
      for (int i = 0; i < 3; ++i)
        c2L[i] = __builtin_amdgcn_mfma_f32_16x16x32_bf16(q0, b2f[i][0], c2L[i], 0, 0, 0);
#pragma unroll
      for (int i = 0; i < 3; ++i)
        c2H[i] = __builtin_amdgcn_mfma_f32_16x16x32_bf16(a1, b2f[i][1], c2H[i], 0, 0, 0);
#pragma unroll
      for (int i = 0; i < 3; ++i)
        c2L[i] = __builtin_amdgcn_mfma_f32_16x16x32_bf16(q1, b2f[i][1], c2L[i], 0, 0, 0);
#pragma unroll
      for (int i = 0; i < 3; ++i)
        c2H[i] = __builtin_amdgcn_mfma_f32_16x16x32_bf16(a2, b2f[i][2], c2H[i], 0, 0, 0);
#pragma unroll
      for (int i = 0; i < 3; ++i)
        c2L[i] = __builtin_amdgcn_mfma_f32_16x16x32_bf16(q2, b2f[i][2], c2L[i], 0, 0, 0);
    }
    if (lq < 2) {
#pragma unroll
      for (int i = 0; i < 3; ++i)
#pragma unroll
        for (int r = 0; r < 4; ++r)
          gsw[w][lq * 4 + r][i * 16 + lj] = c2H[i][r] + c2L[i][r];
    }
    // softmax for p-1 (reads logit_s written phase 1, across B1)
    if (p > 0 && smth) {
      const int n = sm;
      const float l0 = logit_s[0][n], l1 = logit_s[1][n], l2 = logit_s[2][n],
                  l3 = logit_s[3][n], l4 = logit_s[4][n];
      const float m = fmaxf(fmaxf(fmaxf(l0, l1), fmaxf(l2, l3)), l4);
      const float e0 = __expf(l0 - m), e1 = __expf(l1 - m), e2 = __expf(l2 - m),
                  e3 = __expf(l3 - m), e4 = __expf(l4 - m);
      const float rs = __builtin_amdgcn_rcpf(e0 + e1 + e2 + e3 + e4);
      prob_s[0][n] = e0 * rs; prob_s[1][n] = e1 * rs; prob_s[2][n] = e2 * rs;
      prob_s[3][n] = e3 * rs; prob_s[4][n] = e4 * rs;
    }
    lds_wave_fence();
    // L2 activations (wave-local) -> h2(p) into buf[alt] + h2f
    {
      const float ig = gsw[w][an0][au0],      fg = gsw[w][an0][12 + au0];
      const float gg = gsw[w][an0][24 + au0], og = gsw[w][an0][36 + au0];
      const float cc = sigf(fg) * c2s[0] + sigf(ig) * tanh_f(gg);
      c2s[0] = cc;
      const float h = sigf(og) * tanh_f(cc);
      unsigned short hb, lb;
      hsplit(h, hb, lb);
      hh[alt][an0][48 + aug0] = (short)hb;
      hl[alt][an0][48 + aug0] = (short)lb;
      h2f[an0][aug0] = h;
    }
    if (has2) {
      const float ig = gsw[w][an1][au1],      fg = gsw[w][an1][12 + au1];
      const float gg = gsw[w][an1][24 + au1], og = gsw[w][an1][36 + au1];
      const float cc = sigf(fg) * c2s[1] + sigf(ig) * tanh_f(gg);
      c2s[1] = cc;
      const float h = sigf(og) * tanh_f(cc);
      unsigned short hb, lb;
      hsplit(h, hb, lb);
      hh[alt][an1][48 + aug1] = (short)hb;
      hl[alt][an1][48 + aug1] = (short)lb;
      h2f[an1][aug1] = h;
    }
    lds_barrier();  // B2
  }
  // ---- epilogue: logits(P-1) + store(P-2); softmax(P-1); store(P-1) ----
  if (fcth) {
    float a = fcbr;
#pragma unroll
    for (int uq = 0; uq < 12; ++uq) {
      f32x4 hv = *(const f32x4*)&h2f[fn][uq * 4];
      f32x4 wv = *(const f32x4*)&fcws[fk * 48 + uq * 4];
      a += hv[0] * wv[0] + hv[1] * wv[1] + hv[2] * wv[2] + hv[3] * wv[3];
    }
    logit_s[fk][fn] = a;
  }
  if (stth) {
    out[(((size_t)b * P_ + (P_ - 2)) * 5 + sk) * T_ + t0 + sn] = prob_s[sk][sn];
  }
  lds_barrier();
  if (smth) {
    const int n = sm;
    const float l0 = logit_s[0][n], l1 = logit_s[1][n], l2 = logit_s[2][n],
                l3 = logit_s[3][n], l4 = logit_s[4][n];
    const float m = fmaxf(fmaxf(fmaxf(l0, l1), fmaxf(l2, l3)), l4);
    const float e0 = __expf(l0 - m), e1 = __expf(l1 - m), e2 = __expf(l2 - m),
                e3 = __expf(l3 - m), e4 = __expf(l4 - m);
    const float rs = __builtin_amdgcn_rcpf(e0 + e1 + e2 + e3 + e4);
    prob_s[0][n] = e0 * rs; prob_s[1][n] = e1 * rs; prob_s[2][n] = e2 * rs;
    prob_s[3][n] = e3 * rs; prob_s[4][n] = e4 * rs;
  }
  lds_barrier();
  if (stth) {
    out[(((size_t)b * P_ + (P_ - 1)) * 5 + sk) * T_ + t0 + sn] = prob_s[sk][sn];
  }
}

extern "C" void kernel_launch(void* const* d_in, const int* in_sizes, int n_in,
                              void* d_out, int out_size, void* d_ws, size_t ws_size,
                              hipStream_t stream) {
  const float* pf   = (const float*)d_in[0];
  const float* pc   = (const float*)d_in[1];
  const float* fc1w = (const float*)d_in[2];
  const float* fc1b = (const float*)d_in[3];
  const float* fc2w = (const float*)d_in[4];
  const float* fc2b = (const float*)d_in[5];
  const float* fc3w = (const float*)d_in[6];
  const float* fc3b = (const float*)d_in[7];
  const float* wih1 = (const float*)d_in[8];
  const float* whh1 = (const float*)d_in[9];
  const float* bih1 = (const float*)d_in[10];
  const float* bhh1 = (const float*)d_in[11];
  const float* wih2 = (const float*)d_in[12];
  const float* whh2 = (const float*)d_in[13];
  const float* bih2 = (const float*)d_in[14];
  const float* bhh2 = (const float*)d_in[15];
  const float* fcw  = (const float*)d_in[16];
  const float* fcb  = (const float*)d_in[17];
  float* out = (float*)d_out;

  char* wsp = (char*)d_ws;
  float* ctxg = (float*)wsp;                                     // 1,081,344 B
  const size_t CTXG_BYTES = (size_t)B_ * P_ * G_ * sizeof(float);
  f16x8* wfrag = (f16x8*)(wsp + CTXG_BYTES);                     // 73,728 B
  const size_t WFRAG_BYTES = (size_t)12 * 6 * 64 * 16;
  unsigned short* xg2 = (unsigned short*)(wsp + CTXG_BYTES + WFRAG_BYTES);  // ~138.5 MB

  ctx_kernel<<<22, 64, 0, stream>>>(pc, fc1w, fc1b, fc2w, fc2b, fc3w, fc3b,
                                    wih1, bih1, bhh1, ctxg);
  wfrag_kernel<<<18, 256, 0, stream>>>(wih1, wfrag);
  gemm_mfma<<<B_ * P_ * 2, 256, 0, stream>>>(pf, wfrag, ctxg, xg2);
  scan_mfma<<<N_ / 8, 256, 0, stream>>>(xg2, whh1, wih2, whh2,
                                        bih2, bhh2, fcw, fcb, out);
}